// Round 1
// baseline (4180.886 us; speedup 1.0000x reference)
//
#include <hip/hip_runtime.h>

// GCN 2-layer: x1 = relu(Agg(z@W1)+b1), out = relu(Agg(x1@W2)+b2)
// Agg(h)[d] = dinv[d] * ( sum_{e:dst=d} h[src]*dinv[src] + h[d]*dinv[d] )
// Factored: h' = (x@W)*dinv[row];  acc[d] = h'[d] + sum_{e:dst=d} h'[src];
//           next-layer input = relu(acc[d]*dinv[d] + b)

__global__ void deg_count_kernel(const int* __restrict__ dst, int* __restrict__ deg, int E) {
    int i = blockIdx.x * blockDim.x + threadIdx.x;
    if (i < E) atomicAdd(&deg[dst[i]], 1);
}

__global__ void dinv_kernel(float* __restrict__ buf, int N) {
    int i = blockIdx.x * blockDim.x + threadIdx.x;
    if (i < N) {
        int d = reinterpret_cast<const int*>(buf)[i];   // edge count
        buf[i] = rsqrtf((float)(d + 1));                // +1 self-loop; always > 0
    }
}

// h1[N,128] = (z[N,64] @ W[64,128]) * dinv[row], dual-written to h1 and acc1 (self-loop init)
__global__ __launch_bounds__(256) void gemm1_kernel(
    const float* __restrict__ z, const float* __restrict__ W,
    const float* __restrict__ dinv, float* __restrict__ h1,
    float* __restrict__ acc1, int N) {
    __shared__ float wl[64 * 128];
    __shared__ float zl[16 * 64];
    int tid = threadIdx.x;
    for (int i = tid; i < 64 * 128; i += 256) wl[i] = W[i];
    int base = blockIdx.x * 16;
    for (int i = tid; i < 16 * 64; i += 256) {
        int r = i >> 6, c = i & 63;
        int node = base + r;
        zl[i] = (node < N) ? z[node * 64 + c] : 0.f;
    }
    __syncthreads();
    int j = tid & 127, rb = tid >> 7;  // j: out col, rows rb, rb+2, ... rb+14
    float acc[8];
#pragma unroll
    for (int k = 0; k < 8; ++k) acc[k] = 0.f;
    for (int kk = 0; kk < 64; ++kk) {
        float wv = wl[kk * 128 + j];
#pragma unroll
        for (int k = 0; k < 8; ++k)
            acc[k] = fmaf(zl[(rb + 2 * k) * 64 + kk], wv, acc[k]);
    }
#pragma unroll
    for (int k = 0; k < 8; ++k) {
        int node = base + rb + 2 * k;
        if (node < N) {
            float v = acc[k] * dinv[node];
            h1[node * 128 + j] = v;
            acc1[node * 128 + j] = v;
        }
    }
}

// h2[N,64] = (relu(acc1*dinv+b1)[N,128] @ W[128,64]) * dinv[row], dual-written to h2 and out
__global__ __launch_bounds__(256) void gemm2_kernel(
    const float* __restrict__ acc1, const float* __restrict__ b1,
    const float* __restrict__ dinv, const float* __restrict__ W,
    float* __restrict__ h2, float* __restrict__ outacc, int N) {
    __shared__ float wl[128 * 64];
    __shared__ float xl[16 * 128];
    __shared__ float bl[128];
    int tid = threadIdx.x;
    for (int i = tid; i < 128 * 64; i += 256) wl[i] = W[i];
    if (tid < 128) bl[tid] = b1[tid];
    __syncthreads();
    int base = blockIdx.x * 16;
    for (int i = tid; i < 16 * 128; i += 256) {
        int r = i >> 7, c = i & 127;
        int node = base + r;
        float v = 0.f;
        if (node < N) v = fmaf(acc1[node * 128 + c], dinv[node], bl[c]);
        xl[i] = fmaxf(v, 0.f);
    }
    __syncthreads();
    int j = tid & 63, rb = tid >> 6;  // rows rb, rb+4, rb+8, rb+12
    float acc[4] = {0.f, 0.f, 0.f, 0.f};
    for (int kk = 0; kk < 128; ++kk) {
        float wv = wl[kk * 64 + j];
#pragma unroll
        for (int k = 0; k < 4; ++k)
            acc[k] = fmaf(xl[(rb + 4 * k) * 128 + kk], wv, acc[k]);
    }
#pragma unroll
    for (int k = 0; k < 4; ++k) {
        int node = base + rb + 4 * k;
        if (node < N) {
            float v = acc[k] * dinv[node];
            h2[node * 64 + j] = v;
            outacc[node * 64 + j] = v;
        }
    }
}

// acc[dst] += h[src] (unweighted; norm factored into h and epilogue)
template <int F>
__global__ void scatter_kernel(const float* __restrict__ h, const int* __restrict__ src,
                               const int* __restrict__ dst, float* __restrict__ acc, int E) {
    constexpr int Q = F / 4;
    int total = E * Q;
    int stride = gridDim.x * blockDim.x;
    for (int i = blockIdx.x * blockDim.x + threadIdx.x; i < total; i += stride) {
        int e = i / Q, q = i - e * Q;
        int s = src[e], d = dst[e];
        float4 v = reinterpret_cast<const float4*>(h)[s * Q + q];
        float* o = acc + d * F + q * 4;
        atomicAdd(o + 0, v.x);
        atomicAdd(o + 1, v.y);
        atomicAdd(o + 2, v.z);
        atomicAdd(o + 3, v.w);
    }
}

// out = relu(out*dinv[row] + b2[col]), 64 cols, float4-vectorized
__global__ void final_kernel(float* __restrict__ out, const float* __restrict__ dinv,
                             const float* __restrict__ b2, int N) {
    int i = blockIdx.x * blockDim.x + threadIdx.x;
    int total = N * 16;
    if (i >= total) return;
    int node = i >> 4, q = i & 15;
    float w = dinv[node];
    float4 v = reinterpret_cast<float4*>(out)[i];
    float4 b = reinterpret_cast<const float4*>(b2)[q];
    v.x = fmaxf(fmaf(v.x, w, b.x), 0.f);
    v.y = fmaxf(fmaf(v.y, w, b.y), 0.f);
    v.z = fmaxf(fmaf(v.z, w, b.z), 0.f);
    v.w = fmaxf(fmaf(v.w, w, b.w), 0.f);
    reinterpret_cast<float4*>(out)[i] = v;
}

extern "C" void kernel_launch(void* const* d_in, const int* in_sizes, int n_in,
                              void* d_out, int out_size, void* d_ws, size_t ws_size,
                              hipStream_t stream) {
    const float* z  = (const float*)d_in[0];
    const int* edges = (const int*)d_in[1];
    const float* W1 = (const float*)d_in[2];
    const float* b1 = (const float*)d_in[3];
    const float* W2 = (const float*)d_in[4];
    const float* b2 = (const float*)d_in[5];
    float* out = (float*)d_out;

    int N = in_sizes[0] / 64;   // 50000
    int E = in_sizes[1] / 2;    // 1600000
    const int* src = edges;
    const int* dst = edges + E;

    char* ws = (char*)d_ws;
    float* dinv = (float*)ws;                          // N floats (int deg, then dinv in place)
    float* h1   = (float*)(ws + 512 * 1024);           // N*128
    float* acc1 = h1 + (size_t)N * 128;                // N*128
    float* h2   = h1;                                  // alias: h1 dead once gemm2 runs

    hipMemsetAsync(dinv, 0, (size_t)N * sizeof(int), stream);
    deg_count_kernel<<<(E + 255) / 256, 256, 0, stream>>>(dst, (int*)dinv, E);
    dinv_kernel<<<(N + 255) / 256, 256, 0, stream>>>(dinv, N);

    gemm1_kernel<<<(N + 15) / 16, 256, 0, stream>>>(z, W1, dinv, h1, acc1, N);
    scatter_kernel<128><<<16384, 256, 0, stream>>>(h1, src, dst, acc1, E);
    gemm2_kernel<<<(N + 15) / 16, 256, 0, stream>>>(acc1, b1, dinv, W2, h2, out, N);
    scatter_kernel<64><<<16384, 256, 0, stream>>>(h2, src, dst, out, E);
    final_kernel<<<(N * 16 + 255) / 256, 256, 0, stream>>>(out, dinv, b2, N);
}

// Round 2
// 549.256 us; speedup vs baseline: 7.6119x; 7.6119x over previous
//
#include <hip/hip_runtime.h>

// GCN 2-layer, gather (CSR) formulation — no float atomics.
// Agg(h)[d] = dinv[d]*(h'[d] + sum_{e:dst=d} h'[src]) with h' = (x@W)*dinv[row]
// Pipeline: deg count -> scan(rowptr,cursor,dinv) -> CSR fill ->
//           gemm1(h1) -> gather1(x1=relu(..+b1)) -> gemm2(h2) -> gather2(out=relu(..+b2))

__global__ void deg_count_kernel(const int* __restrict__ dst, int* __restrict__ deg, int E) {
    int i = blockIdx.x * blockDim.x + threadIdx.x;
    if (i < E) atomicAdd(&deg[dst[i]], 1);
}

// single block, 1024 threads: exclusive scan of deg -> rowptr, cursor; dinv = rsqrt(deg+1)
__global__ __launch_bounds__(1024) void scan_kernel(
    const int* __restrict__ deg, int* __restrict__ rowptr, int* __restrict__ cursor,
    float* __restrict__ dinv, int N) {
    __shared__ int part[1024];
    int t = threadIdx.x;
    int chunk = (N + 1023) / 1024;
    int lo = t * chunk, hi = min(N, lo + chunk);
    int s = 0;
    for (int i = lo; i < hi; ++i) s += deg[i];
    part[t] = s;
    __syncthreads();
    for (int off = 1; off < 1024; off <<= 1) {
        int v = part[t];
        int add = (t >= off) ? part[t - off] : 0;
        __syncthreads();
        part[t] = v + add;
        __syncthreads();
    }
    int run = (t > 0) ? part[t - 1] : 0;
    for (int i = lo; i < hi; ++i) {
        int d = deg[i];
        rowptr[i] = run;
        cursor[i] = run;
        dinv[i] = rsqrtf((float)(d + 1));
        run += d;
    }
    if (t == 1023) rowptr[N] = run;
}

__global__ void fill_kernel(const int* __restrict__ src, const int* __restrict__ dst,
                            int* __restrict__ cursor, int* __restrict__ csr, int E) {
    int i = blockIdx.x * blockDim.x + threadIdx.x;
    if (i < E) {
        int pos = atomicAdd(&cursor[dst[i]], 1);
        csr[pos] = src[i];
    }
}

// h1[N,128] = (z[N,64] @ W[64,128]) * dinv[row]
__global__ __launch_bounds__(256) void gemm1_kernel(
    const float* __restrict__ z, const float* __restrict__ W,
    const float* __restrict__ dinv, float* __restrict__ h1, int N) {
    __shared__ float wl[64 * 128];
    __shared__ float zl[16 * 64];
    int tid = threadIdx.x;
    for (int i = tid; i < 64 * 128; i += 256) wl[i] = W[i];
    int base = blockIdx.x * 16;
    for (int i = tid; i < 16 * 64; i += 256) {
        int r = i >> 6, c = i & 63;
        int node = base + r;
        zl[i] = (node < N) ? z[node * 64 + c] : 0.f;
    }
    __syncthreads();
    int j = tid & 127, rb = tid >> 7;
    float acc[8];
#pragma unroll
    for (int k = 0; k < 8; ++k) acc[k] = 0.f;
    for (int kk = 0; kk < 64; ++kk) {
        float wv = wl[kk * 128 + j];
#pragma unroll
        for (int k = 0; k < 8; ++k)
            acc[k] = fmaf(zl[(rb + 2 * k) * 64 + kk], wv, acc[k]);
    }
#pragma unroll
    for (int k = 0; k < 8; ++k) {
        int node = base + rb + 2 * k;
        if (node < N) h1[node * 128 + j] = acc[k] * dinv[node];
    }
}

// h2[N,64] = (x1[N,128] @ W[128,64]) * dinv[row]   (x1 already relu(.+b1))
__global__ __launch_bounds__(256) void gemm2_kernel(
    const float* __restrict__ x1, const float* __restrict__ dinv,
    const float* __restrict__ W, float* __restrict__ h2, int N) {
    __shared__ float wl[128 * 64];
    __shared__ float xl[16 * 128];
    int tid = threadIdx.x;
    for (int i = tid; i < 128 * 64; i += 256) wl[i] = W[i];
    int base = blockIdx.x * 16;
    for (int i = tid; i < 16 * 128; i += 256) {
        int r = i >> 7, c = i & 127;
        int node = base + r;
        xl[i] = (node < N) ? x1[node * 128 + c] : 0.f;
    }
    __syncthreads();
    int j = tid & 63, rb = tid >> 6;
    float acc[4] = {0.f, 0.f, 0.f, 0.f};
    for (int kk = 0; kk < 128; ++kk) {
        float wv = wl[kk * 64 + j];
#pragma unroll
        for (int k = 0; k < 4; ++k)
            acc[k] = fmaf(xl[(rb + 4 * k) * 128 + kk], wv, acc[k]);
    }
#pragma unroll
    for (int k = 0; k < 4; ++k) {
        int node = base + rb + 4 * k;
        if (node < N) h2[node * 64 + j] = acc[k] * dinv[node];
    }
}

// One wave per dst node: out[d] = relu((h[d] + sum_{s in adj(d)} h[s]) * dinv[d] + bias)
// VPL=2 -> F=128 (float2/lane), VPL=1 -> F=64 (float/lane)
template <int VPL>
__global__ __launch_bounds__(256) void gather_kernel(
    const float* __restrict__ h, const int* __restrict__ rowptr,
    const int* __restrict__ csr, const float* __restrict__ dinv,
    const float* __restrict__ bias, float* __restrict__ outp, int N) {
    int node = (blockIdx.x * 256 + threadIdx.x) >> 6;
    int lane = threadIdx.x & 63;
    if (node >= N) return;
    int start = rowptr[node], end = rowptr[node + 1];
    float w = dinv[node];
    if constexpr (VPL == 2) {
        const float2* hv = reinterpret_cast<const float2*>(h);
        float2 self = hv[node * 64 + lane];
        float ax = self.x, ay = self.y;
        int k = start;
        for (; k + 4 <= end; k += 4) {
            int s0 = csr[k], s1 = csr[k + 1], s2 = csr[k + 2], s3 = csr[k + 3];
            float2 v0 = hv[s0 * 64 + lane];
            float2 v1 = hv[s1 * 64 + lane];
            float2 v2 = hv[s2 * 64 + lane];
            float2 v3 = hv[s3 * 64 + lane];
            ax += (v0.x + v1.x) + (v2.x + v3.x);
            ay += (v0.y + v1.y) + (v2.y + v3.y);
        }
        for (; k < end; ++k) {
            float2 v = hv[csr[k] * 64 + lane];
            ax += v.x;
            ay += v.y;
        }
        float2 b = reinterpret_cast<const float2*>(bias)[lane];
        float2 o;
        o.x = fmaxf(fmaf(ax, w, b.x), 0.f);
        o.y = fmaxf(fmaf(ay, w, b.y), 0.f);
        reinterpret_cast<float2*>(outp)[node * 64 + lane] = o;
    } else {
        float a = h[node * 64 + lane];
        int k = start;
        for (; k + 4 <= end; k += 4) {
            int s0 = csr[k], s1 = csr[k + 1], s2 = csr[k + 2], s3 = csr[k + 3];
            float v0 = h[s0 * 64 + lane];
            float v1 = h[s1 * 64 + lane];
            float v2 = h[s2 * 64 + lane];
            float v3 = h[s3 * 64 + lane];
            a += (v0 + v1) + (v2 + v3);
        }
        for (; k < end; ++k) a += h[csr[k] * 64 + lane];
        outp[node * 64 + lane] = fmaxf(fmaf(a, w, bias[lane]), 0.f);
    }
}

extern "C" void kernel_launch(void* const* d_in, const int* in_sizes, int n_in,
                              void* d_out, int out_size, void* d_ws, size_t ws_size,
                              hipStream_t stream) {
    const float* z  = (const float*)d_in[0];
    const int* edges = (const int*)d_in[1];
    const float* W1 = (const float*)d_in[2];
    const float* b1 = (const float*)d_in[3];
    const float* W2 = (const float*)d_in[4];
    const float* b2 = (const float*)d_in[5];
    float* out = (float*)d_out;

    int N = in_sizes[0] / 64;   // 50000
    int E = in_sizes[1] / 2;    // 1600000
    const int* src = edges;
    const int* dst = edges + E;

    char* ws = (char*)d_ws;
    int*   deg    = (int*)(ws);                      // N ints
    int*   rowptr = (int*)(ws + 256 * 1024);         // N+1 ints
    int*   cursor = (int*)(ws + 512 * 1024);         // N ints
    float* dinv   = (float*)(ws + 768 * 1024);       // N floats
    int*   csr    = (int*)(ws + 1024 * 1024);        // E ints (6.4 MB)
    float* h1     = (float*)(ws + 8ull * 1024 * 1024);        // N*128 (25.6 MB)
    float* x1     = h1 + (size_t)N * 128;                     // N*128 (25.6 MB)
    float* h2     = h1;  // h1 dead after gather1

    hipMemsetAsync(deg, 0, (size_t)N * sizeof(int), stream);
    deg_count_kernel<<<(E + 255) / 256, 256, 0, stream>>>(dst, deg, E);
    scan_kernel<<<1, 1024, 0, stream>>>(deg, rowptr, cursor, dinv, N);
    fill_kernel<<<(E + 255) / 256, 256, 0, stream>>>(src, dst, cursor, csr, E);

    gemm1_kernel<<<(N + 15) / 16, 256, 0, stream>>>(z, W1, dinv, h1, N);
    gather_kernel<2><<<(N + 3) / 4, 256, 0, stream>>>(h1, rowptr, csr, dinv, b1, x1, N);
    gemm2_kernel<<<(N + 15) / 16, 256, 0, stream>>>(x1, dinv, W2, h2, N);
    gather_kernel<1><<<(N + 3) / 4, 256, 0, stream>>>(h2, rowptr, csr, dinv, b2, out, N);
}

// Round 3
// 381.077 us; speedup vs baseline: 10.9712x; 1.4413x over previous
//
#include <hip/hip_runtime.h>

// GCN 2-layer, CSR gather, aggregate-first layer 1:
//   z' = z*dinv[row];  agg1[d] = dinv[d]*(z'[d] + sum z'[s])   (gather 64-wide)
//   x1 = relu(agg1 @ W1 + b1)
//   h2 = (x1 @ W2)*dinv[row];  out = relu(dinv[d]*(h2[d]+sum h2[s]) + b2)

__global__ void deg_count_kernel(const int* __restrict__ dst, int* __restrict__ deg, int E) {
    int i = blockIdx.x * blockDim.x + threadIdx.x;
    if (i < E) atomicAdd(&deg[dst[i]], 1);
}

// Phase A: per-block (1024 elems) sums
__global__ __launch_bounds__(256) void scanA_kernel(const int* __restrict__ deg,
                                                    int* __restrict__ part, int N) {
    __shared__ int red[256];
    int b = blockIdx.x, t = threadIdx.x;
    int base = b * 1024 + t * 4;
    int s = 0;
    if (base + 3 < N) {
        int4 v = *reinterpret_cast<const int4*>(deg + base);
        s = v.x + v.y + v.z + v.w;
    } else {
        for (int i = 0; i < 4; ++i)
            if (base + i < N) s += deg[base + i];
    }
    red[t] = s;
    __syncthreads();
    for (int off = 128; off > 0; off >>= 1) {
        if (t < off) red[t] += red[t + off];
        __syncthreads();
    }
    if (t == 0) part[b] = red[0];
}

// Phase B: inclusive scan of <=256 block sums, one block
__global__ __launch_bounds__(256) void scanB_kernel(int* __restrict__ part, int nb) {
    __shared__ int sp[256];
    int t = threadIdx.x;
    sp[t] = (t < nb) ? part[t] : 0;
    __syncthreads();
    for (int off = 1; off < 256; off <<= 1) {
        int cur = sp[t];
        int add = (t >= off) ? sp[t - off] : 0;
        __syncthreads();
        sp[t] = cur + add;
        __syncthreads();
    }
    if (t < nb) part[t] = sp[t];
}

// Phase C: per-block exclusive scan + write rowptr/cursor/dinv
__global__ __launch_bounds__(256) void scanC_kernel(
    const int* __restrict__ deg, const int* __restrict__ part, int* __restrict__ rowptr,
    int* __restrict__ cursor, float* __restrict__ dinv, int N) {
    __shared__ int sp[256];
    int b = blockIdx.x, t = threadIdx.x;
    int base = b * 1024 + t * 4;
    int d0 = 0, d1 = 0, d2 = 0, d3 = 0;
    if (base + 3 < N) {
        int4 v = *reinterpret_cast<const int4*>(deg + base);
        d0 = v.x; d1 = v.y; d2 = v.z; d3 = v.w;
    } else {
        if (base < N) d0 = deg[base];
        if (base + 1 < N) d1 = deg[base + 1];
        if (base + 2 < N) d2 = deg[base + 2];
        if (base + 3 < N) d3 = deg[base + 3];
    }
    int local = d0 + d1 + d2 + d3;
    sp[t] = local;
    __syncthreads();
    for (int off = 1; off < 256; off <<= 1) {
        int cur = sp[t];
        int add = (t >= off) ? sp[t - off] : 0;
        __syncthreads();
        sp[t] = cur + add;
        __syncthreads();
    }
    int blockOff = (b > 0) ? part[b - 1] : 0;
    int r0 = blockOff + ((t > 0) ? sp[t - 1] : 0);
    int r1 = r0 + d0, r2 = r1 + d1, r3 = r2 + d2;
    if (base + 3 < N) {
        *reinterpret_cast<int4*>(rowptr + base) = make_int4(r0, r1, r2, r3);
        *reinterpret_cast<int4*>(cursor + base) = make_int4(r0, r1, r2, r3);
        float4 dv = make_float4(rsqrtf((float)(d0 + 1)), rsqrtf((float)(d1 + 1)),
                                rsqrtf((float)(d2 + 1)), rsqrtf((float)(d3 + 1)));
        *reinterpret_cast<float4*>(dinv + base) = dv;
    } else {
        int rr[4] = {r0, r1, r2, r3};
        int dd[4] = {d0, d1, d2, d3};
        for (int i = 0; i < 4; ++i)
            if (base + i < N) {
                rowptr[base + i] = rr[i];
                cursor[base + i] = rr[i];
                dinv[base + i] = rsqrtf((float)(dd[i] + 1));
            }
    }
    if (b == gridDim.x - 1 && t == 255) rowptr[N] = blockOff + sp[255];
}

__global__ void fill_kernel(const int* __restrict__ src, const int* __restrict__ dst,
                            int* __restrict__ cursor, int* __restrict__ csr, int E) {
    int i = blockIdx.x * blockDim.x + threadIdx.x;
    if (i < E) {
        int pos = atomicAdd(&cursor[dst[i]], 1);
        csr[pos] = src[i];
    }
}

// zp = z * dinv[row], float4-vectorized (64 cols)
__global__ void prescale_kernel(const float* __restrict__ z, const float* __restrict__ dinv,
                                float* __restrict__ zp, int N) {
    int i = blockIdx.x * blockDim.x + threadIdx.x;
    if (i >= N * 16) return;
    int node = i >> 4;
    float w = dinv[node];
    float4 v = reinterpret_cast<const float4*>(z)[i];
    v.x *= w; v.y *= w; v.z *= w; v.w *= w;
    reinterpret_cast<float4*>(zp)[i] = v;
}

// One wave per node, 64 floats/row. EPI=0: out=(self+sum)*dinv; EPI=1: out=relu((..)*dinv+bias)
template <int EPI>
__global__ __launch_bounds__(256) void gather64_kernel(
    const float* __restrict__ h, const int* __restrict__ rowptr, const int* __restrict__ csr,
    const float* __restrict__ dinv, const float* __restrict__ bias,
    float* __restrict__ outp, int N) {
    int node = (blockIdx.x * 256 + threadIdx.x) >> 6;
    int lane = threadIdx.x & 63;
    if (node >= N) return;
    int start = rowptr[node], end = rowptr[node + 1];
    float w = dinv[node];
    float a = h[node * 64 + lane];
    int k = start;
    for (; k + 8 <= end; k += 8) {
        int s0 = csr[k], s1 = csr[k + 1], s2 = csr[k + 2], s3 = csr[k + 3];
        int s4 = csr[k + 4], s5 = csr[k + 5], s6 = csr[k + 6], s7 = csr[k + 7];
        float v0 = h[s0 * 64 + lane], v1 = h[s1 * 64 + lane];
        float v2 = h[s2 * 64 + lane], v3 = h[s3 * 64 + lane];
        float v4 = h[s4 * 64 + lane], v5 = h[s5 * 64 + lane];
        float v6 = h[s6 * 64 + lane], v7 = h[s7 * 64 + lane];
        a += ((v0 + v1) + (v2 + v3)) + ((v4 + v5) + (v6 + v7));
    }
    for (; k < end; ++k) a += h[csr[k] * 64 + lane];
    if constexpr (EPI == 1)
        outp[node * 64 + lane] = fmaxf(fmaf(a, w, bias[lane]), 0.f);
    else
        outp[node * 64 + lane] = a * w;
}

// x1[N,128] = relu(agg1[N,64] @ W1[64,128] + b1)
__global__ __launch_bounds__(256) void gemm1_kernel(
    const float* __restrict__ agg1, const float* __restrict__ W,
    const float* __restrict__ b1, float* __restrict__ x1, int N) {
    __shared__ float wl[64 * 128];
    __shared__ float zl[16 * 64];
    __shared__ float bl[128];
    int tid = threadIdx.x;
    for (int i = tid; i < 64 * 128; i += 256) wl[i] = W[i];
    if (tid < 128) bl[tid] = b1[tid];
    int base = blockIdx.x * 16;
    for (int i = tid; i < 16 * 64; i += 256) {
        int r = i >> 6, c = i & 63;
        int node = base + r;
        zl[i] = (node < N) ? agg1[node * 64 + c] : 0.f;
    }
    __syncthreads();
    int j = tid & 127, rb = tid >> 7;
    float acc[8];
#pragma unroll
    for (int k = 0; k < 8; ++k) acc[k] = 0.f;
    for (int kk = 0; kk < 64; ++kk) {
        float wv = wl[kk * 128 + j];
#pragma unroll
        for (int k = 0; k < 8; ++k)
            acc[k] = fmaf(zl[(rb + 2 * k) * 64 + kk], wv, acc[k]);
    }
#pragma unroll
    for (int k = 0; k < 8; ++k) {
        int node = base + rb + 2 * k;
        if (node < N) x1[node * 128 + j] = fmaxf(acc[k] + bl[j], 0.f);
    }
}

// h2[N,64] = (x1[N,128] @ W2[128,64]) * dinv[row]
__global__ __launch_bounds__(256) void gemm2_kernel(
    const float* __restrict__ x1, const float* __restrict__ dinv,
    const float* __restrict__ W, float* __restrict__ h2, int N) {
    __shared__ float wl[128 * 64];
    __shared__ float xl[16 * 128];
    int tid = threadIdx.x;
    for (int i = tid; i < 128 * 64; i += 256) wl[i] = W[i];
    int base = blockIdx.x * 16;
    for (int i = tid; i < 16 * 128; i += 256) {
        int r = i >> 7, c = i & 127;
        int node = base + r;
        xl[i] = (node < N) ? x1[node * 128 + c] : 0.f;
    }
    __syncthreads();
    int j = tid & 63, rb = tid >> 6;
    float acc[4] = {0.f, 0.f, 0.f, 0.f};
    for (int kk = 0; kk < 128; ++kk) {
        float wv = wl[kk * 64 + j];
#pragma unroll
        for (int k = 0; k < 4; ++k)
            acc[k] = fmaf(xl[(rb + 4 * k) * 128 + kk], wv, acc[k]);
    }
#pragma unroll
    for (int k = 0; k < 4; ++k) {
        int node = base + rb + 4 * k;
        if (node < N) h2[node * 64 + j] = acc[k] * dinv[node];
    }
}

extern "C" void kernel_launch(void* const* d_in, const int* in_sizes, int n_in,
                              void* d_out, int out_size, void* d_ws, size_t ws_size,
                              hipStream_t stream) {
    const float* z  = (const float*)d_in[0];
    const int* edges = (const int*)d_in[1];
    const float* W1 = (const float*)d_in[2];
    const float* b1 = (const float*)d_in[3];
    const float* W2 = (const float*)d_in[4];
    const float* b2 = (const float*)d_in[5];
    float* out = (float*)d_out;

    int N = in_sizes[0] / 64;   // 50000
    int E = in_sizes[1] / 2;    // 1600000
    const int* src = edges;
    const int* dst = edges + E;

    const size_t MB = 1024 * 1024;
    char* ws = (char*)d_ws;
    int*   deg    = (int*)(ws);                 // N ints
    int*   part   = (int*)(ws + 256 * 1024);    // <=256 ints
    int*   rowptr = (int*)(ws + 512 * 1024);    // N+1 ints
    int*   cursor = (int*)(ws + 768 * 1024);    // N ints
    float* dinv   = (float*)(ws + 1 * MB);      // N floats
    int*   csr    = (int*)(ws + 2 * MB);        // E ints (6.4 MB)
    float* agg1   = (float*)(ws + 16 * MB);     // N*64  (12.8 MB)
    float* zp     = (float*)(ws + 29 * MB);     // N*64  (12.8 MB)
    float* x1     = (float*)(ws + 42 * MB);     // N*128 (25.6 MB) overlays zp region end
    float* h2     = agg1;                        // agg1 dead after gemm1

    int NB = (N + 1023) / 1024;

    hipMemsetAsync(deg, 0, (size_t)N * sizeof(int), stream);
    deg_count_kernel<<<(E + 255) / 256, 256, 0, stream>>>(dst, deg, E);
    scanA_kernel<<<NB, 256, 0, stream>>>(deg, part, N);
    scanB_kernel<<<1, 256, 0, stream>>>(part, NB);
    scanC_kernel<<<NB, 256, 0, stream>>>(deg, part, rowptr, cursor, dinv, N);
    fill_kernel<<<(E + 255) / 256, 256, 0, stream>>>(src, dst, cursor, csr, E);

    prescale_kernel<<<(N * 16 + 255) / 256, 256, 0, stream>>>(z, dinv, zp, N);
    gather64_kernel<0><<<(N + 3) / 4, 256, 0, stream>>>(zp, rowptr, csr, dinv, nullptr, agg1, N);
    gemm1_kernel<<<(N + 15) / 16, 256, 0, stream>>>(agg1, W1, b1, x1, N);
    gemm2_kernel<<<(N + 15) / 16, 256, 0, stream>>>(x1, dinv, W2, h2, N);
    gather64_kernel<1><<<(N + 3) / 4, 256, 0, stream>>>(h2, rowptr, csr, dinv, b2, out, N);
}